// Round 18
// baseline (93.787 us; speedup 1.0000x reference)
//
#include <hip/hip_runtime.h>
#include <hip/hip_bf16.h>

typedef __attribute__((ext_vector_type(8))) short short8;
typedef __attribute__((ext_vector_type(4))) float f32x4;
typedef __attribute__((ext_vector_type(4))) unsigned int u32x4;

using bf16 = __hip_bfloat16;

#define L_SEQ 2048
#define NB 2
#define DM 1024
#define NH 16
#define NKV 4
#define HDIM 64
#define CAPV 50.0f
#define QSCALE 0.18033688f   // 0.125 * log2(e) * 50-tanh slope

#if __has_builtin(__builtin_amdgcn_exp2f)
#define EXP2(x) __builtin_amdgcn_exp2f(x)
#else
#define EXP2(x) exp2f(x)
#endif

__device__ __forceinline__ unsigned short f2bs(float f) {
  bf16 h = __float2bfloat16(f);
  return __builtin_bit_cast(unsigned short, h);
}

__device__ __forceinline__ float bs2f(unsigned short u) {
  return __bfloat162float(__builtin_bit_cast(bf16, u));
}

__device__ __forceinline__ unsigned int cvt_pk_bf16(float lo, float hi) {
  unsigned int w;
  asm("v_cvt_pk_bf16_f32 %0, %1, %2" : "=v"(w) : "v"(lo), "v"(hi));
  return w;
}

__device__ __forceinline__ void gload_lds16(const void* g, void* l) {
  __builtin_amdgcn_global_load_lds(
      (const __attribute__((address_space(1))) void*)g,
      (__attribute__((address_space(3))) void*)l, 16, 0, 0);
}

// -------- prep: W transposes (z<4) + x -> bf16 conversion (z==4) ------------
__global__ void k_prep(const float* __restrict__ Wq, const float* __restrict__ Wk,
                       const float* __restrict__ Wv, const float* __restrict__ Wo,
                       const float* __restrict__ x,
                       bf16* __restrict__ wqt, bf16* __restrict__ wkt,
                       bf16* __restrict__ wvt, bf16* __restrict__ wot,
                       ushort* __restrict__ xb) {
  const int z = blockIdx.z;
  const int tx = threadIdx.x, ty = threadIdx.y;
  if (z == 4) {
    const int id = blockIdx.y * 32 + blockIdx.x;
    const int tid = ty * 32 + tx;
    const size_t base = (size_t)id * 4096 + (size_t)tid * 16;
    #pragma unroll
    for (int i = 0; i < 4; ++i) {
      float4 v = *reinterpret_cast<const float4*>(x + base + i * 4);
      ushort4 o = make_ushort4(f2bs(v.x), f2bs(v.y), f2bs(v.z), f2bs(v.w));
      *reinterpret_cast<ushort4*>(xb + base + i * 4) = o;
    }
    return;
  }
  __shared__ float tile[32][33];
  const float* W = (z == 0) ? Wq : (z == 1) ? Wk : (z == 2) ? Wv : Wo;
  bf16* Wt = (z == 0) ? wqt : (z == 1) ? wkt : (z == 2) ? wvt : wot;
  const int Ncols = (z == 1 || z == 2) ? 256 : 1024;
  const int bx = blockIdx.x * 32;
  if (bx >= Ncols) return;
  const int by = blockIdx.y * 32;
  #pragma unroll
  for (int j = 0; j < 32; j += 8)
    tile[ty + j][tx] = W[(size_t)(by + ty + j) * Ncols + bx + tx];
  __syncthreads();
  #pragma unroll
  for (int j = 0; j < 32; j += 8)
    Wt[(size_t)(bx + ty + j) * 1024 + by + tx] = __float2bfloat16(tile[tx][ty + j]);
}

// ---------------- GEMM: C[M,N] = A[M,K] @ Bt[N,K]^T, double-buffered ---------
// BM=64, BN=128, BK=64. LDS granule-XOR swizzled (pre-swizzled gload src).
// OUT_MODE: 1 = f32 row-major + bias (Wo) with FUSED split-K combine on the
//               A-staging path (heavy causal blocks reg-stage
//               A = (pO0+pO1)*rcp(d0+d1)); light blocks gload from y (bf16).
//           6 = merged QKV (A = xb bf16 via gload_lds):
//               col<1024 Q fused rms+rope (gamma pre-scaled by QSCALE) -> qb;
//               1024..1279 K fused rms+rope -> kb; >=1280 V -> Vt
template<int OUT_MODE>
__global__ __launch_bounds__(256) void k_gemm(const bf16* __restrict__ A,
                                              const bf16* __restrict__ Bt,
                                              const float* __restrict__ bq,
                                              const float* __restrict__ bk,
                                              const float* __restrict__ bv,
                                              const float* __restrict__ qg,
                                              const float* __restrict__ kg,
                                              const float* __restrict__ rcT,
                                              const float* __restrict__ rsT,
                                              void* __restrict__ out0,
                                              void* __restrict__ out1,
                                              void* __restrict__ out2,
                                              const int* __restrict__ causal_flag,
                                              int M, int Ncols, int K) {
  __shared__ __align__(16) bf16 As[2][64 * 64];
  __shared__ __align__(16) bf16 Bs[2][128 * 64];
  const int t = threadIdx.x;
  const int lane = t & 63;
  const int w = t >> 6;
  const int wr = w >> 1, wc = w & 1;
  const int m0 = blockIdx.y * 64, n0 = blockIdx.x * 128;
  const int lr = lane & 15, lg = lane >> 4;
  const int nkt = K >> 6;

  // fused-combine config (OUT_MODE 1 only)
  bool heavy = false;
  const bf16* pO0 = nullptr;
  const bf16* pO1 = nullptr;
  const float* pdp = nullptr;
  if (OUT_MODE == 1) {
    heavy = ((*causal_flag) != 0) && ((m0 & 1024) != 0);
    pO0 = reinterpret_cast<const bf16*>(out1);
    pO1 = pO0 + (size_t)NB * L_SEQ * DM;
    pdp = reinterpret_cast<const float*>(out2);
  }

  f32x4 acc[2][4];
  #pragma unroll
  for (int m = 0; m < 2; ++m)
    #pragma unroll
    for (int n = 0; n < 4; ++n)
      acc[m][n] = f32x4{0.f, 0.f, 0.f, 0.f};

  // --- staging helpers ---
  short8 ra[2], rb[2];
  float rinv[2];
  auto issueA = [&](int kofs) {  // heavy Wo: load pO halves + denom into regs
    #pragma unroll
    for (int p = 0; p < 2; ++p) {
      const int G = p * 256 + w * 64 + lane;
      const int row = G >> 3, gc = G & 7;
      const int scol = kofs + ((gc ^ (row & 7)) * 8);
      const int grow = m0 + row;
      const int bb = grow >> 11, l = grow & 2047;
      const size_t base = ((size_t)bb * L_SEQ + l) * DM + scol;
      ra[p] = *reinterpret_cast<const short8*>(pO0 + base);
      rb[p] = *reinterpret_cast<const short8*>(pO1 + base);
      const int hh = scol >> 6;
      const float d0 = pdp[((size_t)bb * NH + hh) * L_SEQ + l];
      const float d1 = pdp[(size_t)(NB * NH) * L_SEQ + ((size_t)bb * NH + hh) * L_SEQ + l];
      rinv[p] = __builtin_amdgcn_rcpf(d0 + d1);
    }
  };
  auto writeA = [&](int buf) {  // heavy Wo: combine + ds_write
    #pragma unroll
    for (int p = 0; p < 2; ++p) {
      const int G = p * 256 + w * 64 + lane;
      const ushort* pa = reinterpret_cast<const ushort*>(&ra[p]);
      const ushort* pb = reinterpret_cast<const ushort*>(&rb[p]);
      unsigned int wo[4];
      #pragma unroll
      for (int i = 0; i < 4; ++i) {
        const float lo = (bs2f(pa[2 * i]) + bs2f(pb[2 * i])) * rinv[p];
        const float hi = (bs2f(pa[2 * i + 1]) + bs2f(pb[2 * i + 1])) * rinv[p];
        wo[i] = cvt_pk_bf16(lo, hi);
      }
      u32x4 pk = {wo[0], wo[1], wo[2], wo[3]};
      *reinterpret_cast<short8*>(&As[buf][G * 8]) = __builtin_bit_cast(short8, pk);
    }
  };
  auto gloadA = [&](int buf, int kofs) {
    #pragma unroll
    for (int p = 0; p < 2; ++p) {
      const int Gb = p * 256 + w * 64;
      const int G = Gb + lane;
      const int row = G >> 3, gc = G & 7;
      gload_lds16(&A[(size_t)(m0 + row) * K + kofs + ((gc ^ (row & 7)) * 8)],
                  &As[buf][Gb * 8]);
    }
  };
  auto gloadB = [&](int buf, int kofs) {
    #pragma unroll
    for (int p = 0; p < 4; ++p) {
      const int Gb = p * 256 + w * 64;
      const int G = Gb + lane;
      const int row = G >> 3, gc = G & 7;
      gload_lds16(&Bt[(size_t)(n0 + row) * K + kofs + ((gc ^ (row & 7)) * 8)],
                  &Bs[buf][Gb * 8]);
    }
  };
  auto mfmaStep = [&](int buf) {
    #pragma unroll
    for (int ks = 0; ks < 2; ++ks) {
      short8 af[2], bfr[4];
      #pragma unroll
      for (int m = 0; m < 2; ++m) {
        const int row = wr * 32 + m * 16 + lr;
        af[m] = *reinterpret_cast<const short8*>(
            &As[buf][row * 64 + (((ks * 4 + lg) ^ (row & 7)) * 8)]);
      }
      #pragma unroll
      for (int n = 0; n < 4; ++n) {
        const int row = wc * 64 + n * 16 + lr;
        bfr[n] = *reinterpret_cast<const short8*>(
            &Bs[buf][row * 64 + (((ks * 4 + lg) ^ (row & 7)) * 8)]);
      }
      #pragma unroll
      for (int m = 0; m < 2; ++m)
        #pragma unroll
        for (int n = 0; n < 4; ++n)
          acc[m][n] = __builtin_amdgcn_mfma_f32_16x16x32_bf16(af[m], bfr[n], acc[m][n], 0, 0, 0);
    }
  };

  int cur = 0;
  if (OUT_MODE == 1 && heavy) {
    issueA(0);
    writeA(0);
    gloadB(0, 0);
    for (int kt = 0; kt < nkt; ++kt) {
      __syncthreads();
      if (kt + 1 < nkt) {
        issueA((kt + 1) * 64);          // global loads in flight
        gloadB(cur ^ 1, (kt + 1) * 64);
      }
      mfmaStep(cur);                    // ds_reads precede the writes below
      if (kt + 1 < nkt) writeA(cur ^ 1);
      cur ^= 1;
    }
  } else {
    gloadA(0, 0);
    gloadB(0, 0);
    for (int kt = 0; kt < nkt; ++kt) {
      __syncthreads();
      if (kt + 1 < nkt) {
        gloadA(cur ^ 1, (kt + 1) * 64);
        gloadB(cur ^ 1, (kt + 1) * 64);
      }
      mfmaStep(cur);
      cur ^= 1;
    }
  }

  const int colbase = n0 + wc * 64;  // wave-uniform, 64-col span

  if (OUT_MODE == 1) {
    #pragma unroll
    for (int m = 0; m < 2; ++m) {
      const int row = m0 + wr * 32 + m * 16 + lg * 4;
      #pragma unroll
      for (int n = 0; n < 4; ++n) {
        const int col = colbase + n * 16 + lr;
        const float bvv = bq[col];
        #pragma unroll
        for (int r = 0; r < 4; ++r)
          reinterpret_cast<float*>(out0)[(size_t)(row + r) * Ncols + col] = acc[m][n][r] + bvv;
      }
    }
  } else {
    if (colbase >= 1280) {
      // V: bf16 transposed Vt[b][d][l]
      #pragma unroll
      for (int m = 0; m < 2; ++m) {
        const int row = m0 + wr * 32 + m * 16 + lg * 4;
        const int bb = row >> 11, l = row & 2047;
        #pragma unroll
        for (int n = 0; n < 4; ++n) {
          const int d = colbase - 1280 + n * 16 + lr;
          const float bvv = bv[d];
          ushort4 o;
          o.x = f2bs(acc[m][n][0] + bvv);
          o.y = f2bs(acc[m][n][1] + bvv);
          o.z = f2bs(acc[m][n][2] + bvv);
          o.w = f2bs(acc[m][n][3] + bvv);
          *reinterpret_cast<ushort4*>(
              &reinterpret_cast<bf16*>(out2)[((size_t)bb * 256 + d) * L_SEQ + l]) = o;
        }
      }
    } else {
      // fused bias + RMSNorm + RoPE (Q or K), write (b, head, l, d)
      // Q gamma pre-scaled by QSCALE (softcap scale folded into Q; RoPE is linear)
      const bool isQ = (colbase < 1024);
      const float* bias = isQ ? bq : bk;
      const float* gma = isQ ? qg : kg;
      bf16* dst0 = reinterpret_cast<bf16*>(isQ ? out0 : out1);
      const int cb = isQ ? colbase : (colbase - 1024);
      const int head = cb >> 6;
      const int heads = isQ ? NH : NKV;
      const float gsc = isQ ? QSCALE : 1.0f;
      float g[4];
      #pragma unroll
      for (int n = 0; n < 4; ++n) g[n] = gma[cb + n * 16 + lr] * gsc;
      #pragma unroll
      for (int m = 0; m < 2; ++m) {
        const int row = m0 + wr * 32 + m * 16 + lg * 4;
        float vv[4][4];
        float ss[4] = {0.f, 0.f, 0.f, 0.f};
        #pragma unroll
        for (int n = 0; n < 4; ++n) {
          const float bvv = bias[cb + n * 16 + lr];
          #pragma unroll
          for (int r = 0; r < 4; ++r) {
            vv[n][r] = acc[m][n][r] + bvv;
            ss[r] = fmaf(vv[n][r], vv[n][r], ss[r]);
          }
        }
        #pragma unroll
        for (int r = 0; r < 4; ++r) {
          float s = ss[r];
          s += __shfl_xor(s, 1, 64);
          s += __shfl_xor(s, 2, 64);
          s += __shfl_xor(s, 4, 64);
          s += __shfl_xor(s, 8, 64);
          ss[r] = rsqrtf(s * (1.0f / 64.0f) + 1e-6f);
        }
        float tv[4][4];
        #pragma unroll
        for (int n = 0; n < 4; ++n)
          #pragma unroll
          for (int r = 0; r < 4; ++r)
            tv[n][r] = vv[n][r] * ss[r] * g[n];
        #pragma unroll
        for (int r = 0; r < 4; ++r) {
          const int grow = row + r;
          const int bb = grow >> 11, l = grow & 2047;
          bf16* dst = dst0 + (((size_t)bb * heads + head) * L_SEQ + l) * HDIM;
          #pragma unroll
          for (int n = 0; n < 4; ++n) {
            const int d = n * 16 + lr;
            const float c = rcT[l * HDIM + d];
            const float s2 = rsT[l * HDIM + d];
            const float rot = (n < 2) ? -tv[n ^ 2][r] : tv[n ^ 2][r];
            dst[d] = __float2bfloat16(fmaf(tv[n][r], c, rot * s2));
          }
        }
      }
    }
  }
}

// ---------------- Flash attention: QBLK=128, swapped QK^T, reg-P PV ---------
// Q pre-scaled by QSCALE => softcap is p = xs*(1 - c3*xs^2) - 16 (3 VALU/el).
// sT = mfma(K,Q): lane (lr,lg) holds P[q=lr][keys 16n+4lg+r]. PV uses the
// shared k-permutation pi(ks,i) = 32ks+16(i>>2)+4lg+(i&3): P fragment built
// in-register via v_cvt_pk_bf16_f32; V fragment = 2x b64 pi-permuted reads
// from swizzled Vs. Heavy rows write bf16 pO + f32 pd partials, combined
// inside the Wo GEMM's A-staging.
// T5: setprio(1) around MFMA clusters (4 blocks/CU at diverse phases).
// Prefetch issue split: K right after barrier, V after QK^T.
__global__ __launch_bounds__(256) void k_attn(
    const bf16* __restrict__ qb, const bf16* __restrict__ kb,
    const bf16* __restrict__ vt, bf16* __restrict__ y,
    bf16* __restrict__ pO, float* __restrict__ pd,
    const int* __restrict__ causal_flag) {
  __shared__ __align__(16) bf16 Ks[2][64 * 64];
  __shared__ __align__(16) bf16 Vs[2][64 * 64];

  const int t = threadIdx.x, lane = t & 63, w = t >> 6;
  const int lr = lane & 15, lg = lane >> 4;
  const int jx = blockIdx.x;            // 0..7
  const int bh = blockIdx.y;
  const int half = blockIdx.z;
  const int b = bh >> 4, h = bh & 15;
  const int kvh = h >> 2;
  const bool causal = (*causal_flag) != 0;

  const int T_a = causal ? (2 * jx + 2) : 32;
  const int T_b = causal ? (32 - 2 * jx) : 32;
  const int total = T_a + T_b;
  const int mid = (total + 1) >> 1;     // 17 causal, 32 non-causal
  const int g0 = half ? mid : 0;
  const int g1 = half ? total : mid;

  const bf16* kbase = kb + ((size_t)b * NKV + kvh) * L_SEQ * HDIM;
  const bf16* vbase = vt + ((size_t)b * NKV + kvh) * HDIM * L_SEQ;

  for (int seg = 0; seg < 2; ++seg) {
    const int qp = seg ? (15 - jx) : jx;   // q-pair index 0..15
    const int ts = seg ? T_b : T_a;
    const int base = seg ? T_a : 0;
    const int lo = max(0, g0 - base);
    const int hi = min(ts, g1 - base);
    if (lo >= hi) continue;                // block-uniform

    const int q0 = qp * 128;
    const int wrow = q0 + w * 32;          // wave's 32-row base

    short8 qf[2][2];
    #pragma unroll
    for (int s = 0; s < 2; ++s) {
      const bf16* qrow = qb + (((size_t)bh) * L_SEQ + wrow + s * 16 + lr) * HDIM;
      qf[s][0] = *reinterpret_cast<const short8*>(qrow + lg * 8);
      qf[s][1] = *reinterpret_cast<const short8*>(qrow + 32 + lg * 8);
    }

    f32x4 o0[4], o1[4];
    #pragma unroll
    for (int n = 0; n < 4; ++n) {
      o0[n] = f32x4{0.f, 0.f, 0.f, 0.f};
      o1[n] = f32x4{0.f, 0.f, 0.f, 0.f};
    }
    float plt0 = 0.f, plt1 = 0.f;  // per-lane denom partial (qrow = wrow+s*16+lr)

    __syncthreads();  // protect K/V LDS reuse across segments
    {
      const int k00 = lo * 64;
      #pragma unroll
      for (int i = 0; i < 2; ++i) {
        const int Gb = i * 256 + w * 64;
        const int G = Gb + lane;
        const int row = G >> 3, gc = G & 7;
        gload_lds16(kbase + (size_t)(k00 + row) * HDIM + ((gc ^ (row & 7)) * 8), &Ks[0][Gb * 8]);
        gload_lds16(vbase + (size_t)row * L_SEQ + k00 + ((gc ^ (row & 7)) * 8), &Vs[0][Gb * 8]);
      }
    }
    int cur = 0;

    for (int kt = lo; kt < hi; ++kt) {
      __syncthreads();  // buf[cur] ready

      const bool pre = (kt + 1 < hi);
      const int k0n = (kt + 1) * 64;
      if (pre) {  // K prefetch immediately (V deferred until after QK^T)
        #pragma unroll
        for (int i = 0; i < 2; ++i) {
          const int Gb = i * 256 + w * 64;
          const int G = Gb + lane;
          const int row = G >> 3, gc = G & 7;
          gload_lds16(kbase + (size_t)(k0n + row) * HDIM + ((gc ^ (row & 7)) * 8),
                      &Ks[cur ^ 1][Gb * 8]);
        }
      }

      // sT = K·Q^T both sets; K fragments read once
      f32x4 s0[4], s1[4];
      #pragma unroll
      for (int n = 0; n < 4; ++n) {
        s0[n] = f32x4{0.f, 0.f, 0.f, 0.f};
        s1[n] = f32x4{0.f, 0.f, 0.f, 0.f};
      }
      __builtin_amdgcn_s_setprio(1);
      #pragma unroll
      for (int n = 0; n < 4; ++n) {
        const int krow = n * 16 + lr;
        short8 kf0 = *reinterpret_cast<const short8*>(
            &Ks[cur][krow * 64 + ((lg ^ (krow & 7)) * 8)]);
        short8 kf1 = *reinterpret_cast<const short8*>(
            &Ks[cur][krow * 64 + (((4 + lg) ^ (krow & 7)) * 8)]);
        s0[n] = __builtin_amdgcn_mfma_f32_16x16x32_bf16(kf0, qf[0][0], s0[n], 0, 0, 0);
        s0[n] = __builtin_amdgcn_mfma_f32_16x16x32_bf16(kf1, qf[0][1], s0[n], 0, 0, 0);
        s1[n] = __builtin_amdgcn_mfma_f32_16x16x32_bf16(kf0, qf[1][0], s1[n], 0, 0, 0);
        s1[n] = __builtin_amdgcn_mfma_f32_16x16x32_bf16(kf1, qf[1][1], s1[n], 0, 0, 0);
      }
      __builtin_amdgcn_s_setprio(0);

      if (pre) {  // V prefetch (lands during softmax+PV, before next barrier)
        #pragma unroll
        for (int i = 0; i < 2; ++i) {
          const int Gb = i * 256 + w * 64;
          const int G = Gb + lane;
          const int row = G >> 3, gc = G & 7;
          gload_lds16(vbase + (size_t)row * L_SEQ + k0n + ((gc ^ (row & 7)) * 8),
                      &Vs[cur ^ 1][Gb * 8]);
        }
      }

      // softcap (scale pre-folded into Q): p = xs*(1 - c3*xs^2) - 16
      const int k0 = kt * 64;
      #pragma unroll
      for (int n = 0; n < 4; ++n) {
        #pragma unroll
        for (int r = 0; r < 4; ++r) {
          float xs = s0[n][r];
          s0[n][r] = fmaf(xs, fmaf(xs * xs, -6.40607e-5f, 1.0f), -16.0f);
          xs = s1[n][r];
          s1[n][r] = fmaf(xs, fmaf(xs * xs, -6.40607e-5f, 1.0f), -16.0f);
        }
      }
      // causal mask: key = k0+16n+4lg+r (row of sT), qrow = wrow+s*16+lr (col)
      if (causal && (k0 + 63 > wrow)) {
        #pragma unroll
        for (int n = 0; n < 4; ++n) {
          const int keyb = k0 + n * 16 + lg * 4;
          #pragma unroll
          for (int r = 0; r < 4; ++r)
            if (keyb + r > wrow + lr) s0[n][r] = -1e30f;
        }
      }
      if (causal && (k0 + 63 > wrow + 16)) {
        #pragma unroll
        for (int n = 0; n < 4; ++n) {
          const int keyb = k0 + n * 16 + lg * 4;
          #pragma unroll
          for (int r = 0; r < 4; ++r)
            if (keyb + r > wrow + 16 + lr) s1[n][r] = -1e30f;
        }
      }

      // exp2 + in-register bf16 pack: w[2n+rh] = pk(p[n][2rh], p[n][2rh+1])
      unsigned int w0[8], w1[8];
      #pragma unroll
      for (int n = 0; n < 4; ++n) {
        const float a0 = EXP2(s0[n][0]);
        const float a1 = EXP2(s0[n][1]);
        const float a2 = EXP2(s0[n][2]);
        const float a3 = EXP2(s0[n][3]);
        plt0 += (a0 + a1) + (a2 + a3);
        w0[2 * n] = cvt_pk_bf16(a0, a1);
        w0[2 * n + 1] = cvt_pk_bf16(a2, a3);
        const float c0 = EXP2(s1[n][0]);
        const float c1 = EXP2(s1[n][1]);
        const float c2 = EXP2(s1[n][2]);
        const float c3 = EXP2(s1[n][3]);
        plt1 += (c0 + c1) + (c2 + c3);
        w1[2 * n] = cvt_pk_bf16(c0, c1);
        w1[2 * n + 1] = cvt_pk_bf16(c2, c3);
      }
      short8 pf0[2], pf1[2];
      #pragma unroll
      for (int ks = 0; ks < 2; ++ks) {
        u32x4 a = {w0[4 * ks], w0[4 * ks + 1], w0[4 * ks + 2], w0[4 * ks + 3]};
        u32x4 c = {w1[4 * ks], w1[4 * ks + 1], w1[4 * ks + 2], w1[4 * ks + 3]};
        pf0[ks] = __builtin_bit_cast(short8, a);
        pf1[ks] = __builtin_bit_cast(short8, c);
      }

      // PV both sets; V fragment = 2x b64 at pi-permuted cols (shared)
      const int voff = 4 * (lg & 1);
      __builtin_amdgcn_s_setprio(1);
      #pragma unroll
      for (int ks = 0; ks < 2; ++ks) {
        const int gA = 4 * ks + (lg >> 1);
        #pragma unroll
        for (int n = 0; n < 4; ++n) {
          const int vd = n * 16 + lr;
          const int vb_ = vd * 64;
          const int sw = vd & 7;
          const uint2 vlo = *reinterpret_cast<const uint2*>(
              &Vs[cur][vb_ + ((gA ^ sw) * 8 + voff)]);
          const uint2 vhi = *reinterpret_cast<const uint2*>(
              &Vs[cur][vb_ + (((gA + 2) ^ sw) * 8 + voff)]);
          u32x4 vv = {vlo.x, vlo.y, vhi.x, vhi.y};
          short8 vfr = __builtin_bit_cast(short8, vv);
          o0[n] = __builtin_amdgcn_mfma_f32_16x16x32_bf16(pf0[ks], vfr, o0[n], 0, 0, 0);
          o1[n] = __builtin_amdgcn_mfma_f32_16x16x32_bf16(pf1[ks], vfr, o1[n], 0, 0, 0);
        }
      }
      __builtin_amdgcn_s_setprio(0);
      cur ^= 1;
    }

    // epilogue per set
    const bool full = (lo == 0) && (hi == ts);
    #pragma unroll
    for (int s = 0; s < 2; ++s) {
      float ls = s ? plt1 : plt0;
      ls += __shfl_xor(ls, 16, 64);
      ls += __shfl_xor(ls, 32, 64);
      // every lane now holds denom for qrow = wrow + s*16 + lr
      const f32x4* oa = s ? o1 : o0;
      if (full) {
        #pragma unroll
        for (int r = 0; r < 4; ++r) {
          const float den = __shfl(ls, lg * 4 + r, 64);  // denom of row lg*4+r
          const float invl = __builtin_amdgcn_rcpf(den);
          const int qg_ = wrow + s * 16 + lg * 4 + r;
          #pragma unroll
          for (int n = 0; n < 4; ++n)
            y[((size_t)b * L_SEQ + qg_) * DM + h * HDIM + n * 16 + lr] =
                __float2bfloat16(oa[n][r] * invl);
        }
      } else {
        if (lane < 16)
          pd[((size_t)half * NB * NH + bh) * L_SEQ + wrow + s * 16 + lane] = ls;
        #pragma unroll
        for (int r = 0; r < 4; ++r) {
          const int qg_ = wrow + s * 16 + lg * 4 + r;
          #pragma unroll
          for (int n = 0; n < 4; ++n)
            pO[(((size_t)half * NB + b) * L_SEQ + qg_) * DM + h * HDIM + n * 16 + lr] =
                __float2bfloat16(oa[n][r]);
        }
      }
    }
  }
}

extern "C" void kernel_launch(void* const* d_in, const int* in_sizes, int n_in,
                              void* d_out, int out_size, void* d_ws, size_t ws_size,
                              hipStream_t stream) {
  (void)in_sizes; (void)n_in; (void)out_size; (void)ws_size;
  const float* x  = (const float*)d_in[0];
  const float* Wq = (const float*)d_in[1];
  const float* bq = (const float*)d_in[2];
  const float* Wk = (const float*)d_in[3];
  const float* bk = (const float*)d_in[4];
  const float* Wv = (const float*)d_in[5];
  const float* bv = (const float*)d_in[6];
  const float* Wo = (const float*)d_in[7];
  const float* bo = (const float*)d_in[8];
  const float* qg = (const float*)d_in[9];
  const float* kg = (const float*)d_in[10];
  const float* rc = (const float*)d_in[11];
  const float* rs = (const float*)d_in[12];
  const int* causal = (const int*)d_in[13];
  float* out = (float*)d_out;

  char* ws = (char*)d_ws;
  size_t off = 0;
  auto alloc = [&](size_t bytes) -> char* {
    char* p = ws + off;
    off += (bytes + 255) & ~(size_t)255;
    return p;
  };
  bf16* xb    = (bf16*)alloc((size_t)4096 * 1024 * 2);
  bf16* wqkvt = (bf16*)alloc((size_t)1536 * 1024 * 2);
  bf16* wot   = (bf16*)alloc((size_t)1024 * 1024 * 2);
  bf16* vt    = (bf16*)alloc((size_t)NB * NKV * HDIM * L_SEQ * 2);
  bf16* qb    = (bf16*)alloc((size_t)NB * NH * L_SEQ * HDIM * 2);
  bf16* kb    = (bf16*)alloc((size_t)NB * NKV * L_SEQ * HDIM * 2);
  bf16* y     = (bf16*)alloc((size_t)4096 * 1024 * 2);
  bf16* pO    = (bf16*)alloc((size_t)2 * NB * L_SEQ * DM * 2);
  float* pd   = (float*)alloc((size_t)2 * NB * NH * L_SEQ * 4);
  bf16* wqt   = wqkvt;
  bf16* wkt   = wqkvt + (size_t)1024 * 1024;
  bf16* wvt   = wqkvt + (size_t)1280 * 1024;

  // prep: 4 weight transposes + x->bf16 conversion in one launch
  k_prep<<<dim3(32, 32, 5), dim3(32, 8), 0, stream>>>(Wq, Wk, Wv, Wo, x,
                                                      wqt, wkt, wvt, wot, (ushort*)xb);

  // merged QKV projection: Q fused rms+rope (gamma pre-scaled) -> qb,
  // K fused -> kb, V -> Vt
  k_gemm<6><<<dim3(12, 64), 256, 0, stream>>>(xb, wqkvt, bq, bk, bv, qg, kg, rc, rs,
                                              qb, kb, vt, causal, 4096, 1536, 1024);

  k_attn<<<dim3(8, NB * NH, 2), 256, 0, stream>>>(qb, kb, vt, y, pO, pd, causal);

  // Wo projection with fused split-K combine on heavy causal rows
  k_gemm<1><<<dim3(8, 64), 256, 0, stream>>>(y, wot, bo, nullptr, nullptr, nullptr, nullptr,
                                             nullptr, nullptr, out, pO, pd, causal,
                                             4096, 1024, 1024);
}

// Round 19
// 93.388 us; speedup vs baseline: 1.0043x; 1.0043x over previous
//
#include <hip/hip_runtime.h>
#include <hip/hip_bf16.h>

typedef __attribute__((ext_vector_type(8))) short short8;
typedef __attribute__((ext_vector_type(4))) float f32x4;
typedef __attribute__((ext_vector_type(4))) unsigned int u32x4;

using bf16 = __hip_bfloat16;

#define L_SEQ 2048
#define NB 2
#define DM 1024
#define NH 16
#define NKV 4
#define HDIM 64
#define CAPV 50.0f
#define QSCALE 0.18033688f   // 0.125 * log2(e) * 50-tanh slope

#if __has_builtin(__builtin_amdgcn_exp2f)
#define EXP2(x) __builtin_amdgcn_exp2f(x)
#else
#define EXP2(x) exp2f(x)
#endif

__device__ __forceinline__ unsigned short f2bs(float f) {
  bf16 h = __float2bfloat16(f);
  return __builtin_bit_cast(unsigned short, h);
}

__device__ __forceinline__ float bs2f(unsigned short u) {
  return __bfloat162float(__builtin_bit_cast(bf16, u));
}

__device__ __forceinline__ unsigned int cvt_pk_bf16(float lo, float hi) {
  unsigned int w;
  asm("v_cvt_pk_bf16_f32 %0, %1, %2" : "=v"(w) : "v"(lo), "v"(hi));
  return w;
}

__device__ __forceinline__ void gload_lds16(const void* g, void* l) {
  __builtin_amdgcn_global_load_lds(
      (const __attribute__((address_space(1))) void*)g,
      (__attribute__((address_space(3))) void*)l, 16, 0, 0);
}

// -------- prep: W transposes (z<4) + x -> bf16 conversion (z==4) ------------
__global__ void k_prep(const float* __restrict__ Wq, const float* __restrict__ Wk,
                       const float* __restrict__ Wv, const float* __restrict__ Wo,
                       const float* __restrict__ x,
                       bf16* __restrict__ wqt, bf16* __restrict__ wkt,
                       bf16* __restrict__ wvt, bf16* __restrict__ wot,
                       ushort* __restrict__ xb) {
  const int z = blockIdx.z;
  const int tx = threadIdx.x, ty = threadIdx.y;
  if (z == 4) {
    const int id = blockIdx.y * 32 + blockIdx.x;
    const int tid = ty * 32 + tx;
    const size_t base = (size_t)id * 4096 + (size_t)tid * 16;
    #pragma unroll
    for (int i = 0; i < 4; ++i) {
      float4 v = *reinterpret_cast<const float4*>(x + base + i * 4);
      ushort4 o = make_ushort4(f2bs(v.x), f2bs(v.y), f2bs(v.z), f2bs(v.w));
      *reinterpret_cast<ushort4*>(xb + base + i * 4) = o;
    }
    return;
  }
  __shared__ float tile[32][33];
  const float* W = (z == 0) ? Wq : (z == 1) ? Wk : (z == 2) ? Wv : Wo;
  bf16* Wt = (z == 0) ? wqt : (z == 1) ? wkt : (z == 2) ? wvt : wot;
  const int Ncols = (z == 1 || z == 2) ? 256 : 1024;
  const int bx = blockIdx.x * 32;
  if (bx >= Ncols) return;
  const int by = blockIdx.y * 32;
  #pragma unroll
  for (int j = 0; j < 32; j += 8)
    tile[ty + j][tx] = W[(size_t)(by + ty + j) * Ncols + bx + tx];
  __syncthreads();
  #pragma unroll
  for (int j = 0; j < 32; j += 8)
    Wt[(size_t)(bx + ty + j) * 1024 + by + tx] = __float2bfloat16(tile[tx][ty + j]);
}

// ---------------- GEMM: C[M,N] = A[M,K] @ Bt[N,K]^T, double-buffered ---------
// BM=64, BN=128, BK=64. LDS granule-XOR swizzled (pre-swizzled gload src).
// OUT_MODE: 1 = f32 row-major + bias (Wo) with FUSED split-K combine on the
//               A-staging path (heavy causal blocks reg-stage
//               A = (pO0+pO1)*rcp(d0+d1)); light blocks gload from y (bf16).
//           6 = merged QKV (A = xb bf16 via gload_lds):
//               col<1024 Q fused rms+rope (gamma pre-scaled by QSCALE) -> qb;
//               1024..1279 K fused rms+rope -> kb; >=1280 V -> Vt
template<int OUT_MODE>
__global__ __launch_bounds__(256) void k_gemm(const bf16* __restrict__ A,
                                              const bf16* __restrict__ Bt,
                                              const float* __restrict__ bq,
                                              const float* __restrict__ bk,
                                              const float* __restrict__ bv,
                                              const float* __restrict__ qg,
                                              const float* __restrict__ kg,
                                              const float* __restrict__ rcT,
                                              const float* __restrict__ rsT,
                                              void* __restrict__ out0,
                                              void* __restrict__ out1,
                                              void* __restrict__ out2,
                                              const int* __restrict__ causal_flag,
                                              int M, int Ncols, int K) {
  __shared__ __align__(16) bf16 As[2][64 * 64];
  __shared__ __align__(16) bf16 Bs[2][128 * 64];
  const int t = threadIdx.x;
  const int lane = t & 63;
  const int w = t >> 6;
  const int wr = w >> 1, wc = w & 1;
  const int m0 = blockIdx.y * 64, n0 = blockIdx.x * 128;
  const int lr = lane & 15, lg = lane >> 4;
  const int nkt = K >> 6;

  // fused-combine config (OUT_MODE 1 only)
  bool heavy = false;
  const bf16* pO0 = nullptr;
  const bf16* pO1 = nullptr;
  const float* pdp = nullptr;
  if (OUT_MODE == 1) {
    heavy = ((*causal_flag) != 0) && ((m0 & 1024) != 0);
    pO0 = reinterpret_cast<const bf16*>(out1);
    pO1 = pO0 + (size_t)NB * L_SEQ * DM;
    pdp = reinterpret_cast<const float*>(out2);
  }

  f32x4 acc[2][4];
  #pragma unroll
  for (int m = 0; m < 2; ++m)
    #pragma unroll
    for (int n = 0; n < 4; ++n)
      acc[m][n] = f32x4{0.f, 0.f, 0.f, 0.f};

  // --- staging helpers ---
  short8 ra[2], rb[2];
  float rinv[2];
  auto issueA = [&](int kofs) {  // heavy Wo: load pO halves + denom into regs
    #pragma unroll
    for (int p = 0; p < 2; ++p) {
      const int G = p * 256 + w * 64 + lane;
      const int row = G >> 3, gc = G & 7;
      const int scol = kofs + ((gc ^ (row & 7)) * 8);
      const int grow = m0 + row;
      const int bb = grow >> 11, l = grow & 2047;
      const size_t base = ((size_t)bb * L_SEQ + l) * DM + scol;
      ra[p] = *reinterpret_cast<const short8*>(pO0 + base);
      rb[p] = *reinterpret_cast<const short8*>(pO1 + base);
      const int hh = scol >> 6;
      const float d0 = pdp[((size_t)bb * NH + hh) * L_SEQ + l];
      const float d1 = pdp[(size_t)(NB * NH) * L_SEQ + ((size_t)bb * NH + hh) * L_SEQ + l];
      rinv[p] = __builtin_amdgcn_rcpf(d0 + d1);
    }
  };
  auto writeA = [&](int buf) {  // heavy Wo: combine + ds_write
    #pragma unroll
    for (int p = 0; p < 2; ++p) {
      const int G = p * 256 + w * 64 + lane;
      const ushort* pa = reinterpret_cast<const ushort*>(&ra[p]);
      const ushort* pb = reinterpret_cast<const ushort*>(&rb[p]);
      unsigned int wo[4];
      #pragma unroll
      for (int i = 0; i < 4; ++i) {
        const float lo = (bs2f(pa[2 * i]) + bs2f(pb[2 * i])) * rinv[p];
        const float hi = (bs2f(pa[2 * i + 1]) + bs2f(pb[2 * i + 1])) * rinv[p];
        wo[i] = cvt_pk_bf16(lo, hi);
      }
      u32x4 pk = {wo[0], wo[1], wo[2], wo[3]};
      *reinterpret_cast<short8*>(&As[buf][G * 8]) = __builtin_bit_cast(short8, pk);
    }
  };
  auto gloadA = [&](int buf, int kofs) {
    #pragma unroll
    for (int p = 0; p < 2; ++p) {
      const int Gb = p * 256 + w * 64;
      const int G = Gb + lane;
      const int row = G >> 3, gc = G & 7;
      gload_lds16(&A[(size_t)(m0 + row) * K + kofs + ((gc ^ (row & 7)) * 8)],
                  &As[buf][Gb * 8]);
    }
  };
  auto gloadB = [&](int buf, int kofs) {
    #pragma unroll
    for (int p = 0; p < 4; ++p) {
      const int Gb = p * 256 + w * 64;
      const int G = Gb + lane;
      const int row = G >> 3, gc = G & 7;
      gload_lds16(&Bt[(size_t)(n0 + row) * K + kofs + ((gc ^ (row & 7)) * 8)],
                  &Bs[buf][Gb * 8]);
    }
  };
  auto mfmaStep = [&](int buf) {
    #pragma unroll
    for (int ks = 0; ks < 2; ++ks) {
      short8 af[2], bfr[4];
      #pragma unroll
      for (int m = 0; m < 2; ++m) {
        const int row = wr * 32 + m * 16 + lr;
        af[m] = *reinterpret_cast<const short8*>(
            &As[buf][row * 64 + (((ks * 4 + lg) ^ (row & 7)) * 8)]);
      }
      #pragma unroll
      for (int n = 0; n < 4; ++n) {
        const int row = wc * 64 + n * 16 + lr;
        bfr[n] = *reinterpret_cast<const short8*>(
            &Bs[buf][row * 64 + (((ks * 4 + lg) ^ (row & 7)) * 8)]);
      }
      #pragma unroll
      for (int m = 0; m < 2; ++m)
        #pragma unroll
        for (int n = 0; n < 4; ++n)
          acc[m][n] = __builtin_amdgcn_mfma_f32_16x16x32_bf16(af[m], bfr[n], acc[m][n], 0, 0, 0);
    }
  };

  int cur = 0;
  if (OUT_MODE == 1 && heavy) {
    issueA(0);
    writeA(0);
    gloadB(0, 0);
    for (int kt = 0; kt < nkt; ++kt) {
      __syncthreads();
      if (kt + 1 < nkt) {
        issueA((kt + 1) * 64);          // global loads in flight
        gloadB(cur ^ 1, (kt + 1) * 64);
      }
      mfmaStep(cur);                    // ds_reads precede the writes below
      if (kt + 1 < nkt) writeA(cur ^ 1);
      cur ^= 1;
    }
  } else {
    gloadA(0, 0);
    gloadB(0, 0);
    for (int kt = 0; kt < nkt; ++kt) {
      __syncthreads();
      if (kt + 1 < nkt) {
        gloadA(cur ^ 1, (kt + 1) * 64);
        gloadB(cur ^ 1, (kt + 1) * 64);
      }
      mfmaStep(cur);
      cur ^= 1;
    }
  }

  const int colbase = n0 + wc * 64;  // wave-uniform, 64-col span

  if (OUT_MODE == 1) {
    #pragma unroll
    for (int m = 0; m < 2; ++m) {
      const int row = m0 + wr * 32 + m * 16 + lg * 4;
      #pragma unroll
      for (int n = 0; n < 4; ++n) {
        const int col = colbase + n * 16 + lr;
        const float bvv = bq[col];
        #pragma unroll
        for (int r = 0; r < 4; ++r)
          reinterpret_cast<float*>(out0)[(size_t)(row + r) * Ncols + col] = acc[m][n][r] + bvv;
      }
    }
  } else {
    if (colbase >= 1280) {
      // V: bf16 transposed Vt[b][d][l]
      #pragma unroll
      for (int m = 0; m < 2; ++m) {
        const int row = m0 + wr * 32 + m * 16 + lg * 4;
        const int bb = row >> 11, l = row & 2047;
        #pragma unroll
        for (int n = 0; n < 4; ++n) {
          const int d = colbase - 1280 + n * 16 + lr;
          const float bvv = bv[d];
          ushort4 o;
          o.x = f2bs(acc[m][n][0] + bvv);
          o.y = f2bs(acc[m][n][1] + bvv);
          o.z = f2bs(acc[m][n][2] + bvv);
          o.w = f2bs(acc[m][n][3] + bvv);
          *reinterpret_cast<ushort4*>(
              &reinterpret_cast<bf16*>(out2)[((size_t)bb * 256 + d) * L_SEQ + l]) = o;
        }
      }
    } else {
      // fused bias + RMSNorm + RoPE (Q or K), write (b, head, l, d)
      // Q gamma pre-scaled by QSCALE (softcap scale folded into Q; RoPE is linear)
      const bool isQ = (colbase < 1024);
      const float* bias = isQ ? bq : bk;
      const float* gma = isQ ? qg : kg;
      bf16* dst0 = reinterpret_cast<bf16*>(isQ ? out0 : out1);
      const int cb = isQ ? colbase : (colbase - 1024);
      const int head = cb >> 6;
      const int heads = isQ ? NH : NKV;
      const float gsc = isQ ? QSCALE : 1.0f;
      float g[4];
      #pragma unroll
      for (int n = 0; n < 4; ++n) g[n] = gma[cb + n * 16 + lr] * gsc;
      #pragma unroll
      for (int m = 0; m < 2; ++m) {
        const int row = m0 + wr * 32 + m * 16 + lg * 4;
        float vv[4][4];
        float ss[4] = {0.f, 0.f, 0.f, 0.f};
        #pragma unroll
        for (int n = 0; n < 4; ++n) {
          const float bvv = bias[cb + n * 16 + lr];
          #pragma unroll
          for (int r = 0; r < 4; ++r) {
            vv[n][r] = acc[m][n][r] + bvv;
            ss[r] = fmaf(vv[n][r], vv[n][r], ss[r]);
          }
        }
        #pragma unroll
        for (int r = 0; r < 4; ++r) {
          float s = ss[r];
          s += __shfl_xor(s, 1, 64);
          s += __shfl_xor(s, 2, 64);
          s += __shfl_xor(s, 4, 64);
          s += __shfl_xor(s, 8, 64);
          ss[r] = rsqrtf(s * (1.0f / 64.0f) + 1e-6f);
        }
        float tv[4][4];
        #pragma unroll
        for (int n = 0; n < 4; ++n)
          #pragma unroll
          for (int r = 0; r < 4; ++r)
            tv[n][r] = vv[n][r] * ss[r] * g[n];
        #pragma unroll
        for (int r = 0; r < 4; ++r) {
          const int grow = row + r;
          const int bb = grow >> 11, l = grow & 2047;
          bf16* dst = dst0 + (((size_t)bb * heads + head) * L_SEQ + l) * HDIM;
          #pragma unroll
          for (int n = 0; n < 4; ++n) {
            const int d = n * 16 + lr;
            const float c = rcT[l * HDIM + d];
            const float s2 = rsT[l * HDIM + d];
            const float rot = (n < 2) ? -tv[n ^ 2][r] : tv[n ^ 2][r];
            dst[d] = __float2bfloat16(fmaf(tv[n][r], c, rot * s2));
          }
        }
      }
    }
  }
}

// ---------------- Flash attention: QBLK=128, swapped QK^T, reg-P PV ---------
// T4 counted-vmcnt pipeline: K triple-buffered (depth-2 prefetch), V double-
// buffered (depth-1). Per iter: s_waitcnt vmcnt(2) (K(kt+1)'s 2 loads stay in
// flight across the barrier; V issued before K each iter so oldest-first
// count forces K(kt),V(kt) landed) -> raw s_barrier -> issue V(kt+1), K(kt+2)
// -> compute. No vmcnt(0) drain in the steady loop. LDS 40KB = 4 blocks/CU.
__global__ __launch_bounds__(256) void k_attn(
    const bf16* __restrict__ qb, const bf16* __restrict__ kb,
    const bf16* __restrict__ vt, bf16* __restrict__ y,
    bf16* __restrict__ pO, float* __restrict__ pd,
    const int* __restrict__ causal_flag) {
  __shared__ __align__(16) bf16 Ks[3][64 * 64];
  __shared__ __align__(16) bf16 Vs[2][64 * 64];

  const int t = threadIdx.x, lane = t & 63, w = t >> 6;
  const int lr = lane & 15, lg = lane >> 4;
  const int jx = blockIdx.x;            // 0..7
  const int bh = blockIdx.y;
  const int half = blockIdx.z;
  const int b = bh >> 4, h = bh & 15;
  const int kvh = h >> 2;
  const bool causal = (*causal_flag) != 0;

  const int T_a = causal ? (2 * jx + 2) : 32;
  const int T_b = causal ? (32 - 2 * jx) : 32;
  const int total = T_a + T_b;
  const int mid = (total + 1) >> 1;     // 17 causal, 32 non-causal
  const int g0 = half ? mid : 0;
  const int g1 = half ? total : mid;

  const bf16* kbase = kb + ((size_t)b * NKV + kvh) * L_SEQ * HDIM;
  const bf16* vbase = vt + ((size_t)b * NKV + kvh) * HDIM * L_SEQ;

  // stage helpers: 2 gload_lds16 each per wave (wave-uniform LDS base)
  auto stageK = [&](int j, int buf) {
    const int kj = j * 64;
    #pragma unroll
    for (int i = 0; i < 2; ++i) {
      const int Gb = i * 256 + w * 64;
      const int G = Gb + lane;
      const int row = G >> 3, gc = G & 7;
      gload_lds16(kbase + (size_t)(kj + row) * HDIM + ((gc ^ (row & 7)) * 8),
                  &Ks[buf][Gb * 8]);
    }
  };
  auto stageV = [&](int j, int buf) {
    const int kj = j * 64;
    #pragma unroll
    for (int i = 0; i < 2; ++i) {
      const int Gb = i * 256 + w * 64;
      const int G = Gb + lane;
      const int row = G >> 3, gc = G & 7;
      gload_lds16(vbase + (size_t)row * L_SEQ + kj + ((gc ^ (row & 7)) * 8),
                  &Vs[buf][Gb * 8]);
    }
  };

  for (int seg = 0; seg < 2; ++seg) {
    const int qp = seg ? (15 - jx) : jx;   // q-pair index 0..15
    const int ts = seg ? T_b : T_a;
    const int base = seg ? T_a : 0;
    const int lo = max(0, g0 - base);
    const int hi = min(ts, g1 - base);
    if (lo >= hi) continue;                // block-uniform

    const int q0 = qp * 128;
    const int wrow = q0 + w * 32;          // wave's 32-row base

    short8 qf[2][2];
    #pragma unroll
    for (int s = 0; s < 2; ++s) {
      const bf16* qrow = qb + (((size_t)bh) * L_SEQ + wrow + s * 16 + lr) * HDIM;
      qf[s][0] = *reinterpret_cast<const short8*>(qrow + lg * 8);
      qf[s][1] = *reinterpret_cast<const short8*>(qrow + 32 + lg * 8);
    }

    f32x4 o0[4], o1[4];
    #pragma unroll
    for (int n = 0; n < 4; ++n) {
      o0[n] = f32x4{0.f, 0.f, 0.f, 0.f};
      o1[n] = f32x4{0.f, 0.f, 0.f, 0.f};
    }
    float plt0 = 0.f, plt1 = 0.f;  // per-lane denom partial (qrow = wrow+s*16+lr)

    __syncthreads();  // segment boundary: full drain, protects LDS reuse
    // prologue: V(lo), K(lo), K(lo+1)  (issue order matters for vmcnt proof)
    stageV(lo, 0);
    stageK(lo, 0);
    if (lo + 1 < hi) stageK(lo + 1, 1);

    int k3 = 0, v2 = 0;
    for (int kt = lo; kt < hi; ++kt) {
      // wait: K(kt), V(kt) landed; allow K(kt+1)'s 2 loads in flight
      if (kt + 1 < hi) {
        asm volatile("s_waitcnt vmcnt(2)" ::: "memory");
      } else {
        asm volatile("s_waitcnt vmcnt(0)" ::: "memory");
      }
      __builtin_amdgcn_s_barrier();
      __builtin_amdgcn_sched_barrier(0);

      // issue next stages (V before K; overwritten bufs were freed by barrier)
      if (kt + 1 < hi) stageV(kt + 1, v2 ^ 1);
      if (kt + 2 < hi) stageK(kt + 2, (k3 + 2) % 3);

      // sT = K·Q^T both sets; K fragments read once
      f32x4 s0[4], s1[4];
      #pragma unroll
      for (int n = 0; n < 4; ++n) {
        s0[n] = f32x4{0.f, 0.f, 0.f, 0.f};
        s1[n] = f32x4{0.f, 0.f, 0.f, 0.f};
      }
      __builtin_amdgcn_s_setprio(1);
      #pragma unroll
      for (int n = 0; n < 4; ++n) {
        const int krow = n * 16 + lr;
        short8 kf0 = *reinterpret_cast<const short8*>(
            &Ks[k3][krow * 64 + ((lg ^ (krow & 7)) * 8)]);
        short8 kf1 = *reinterpret_cast<const short8*>(
            &Ks[k3][krow * 64 + (((4 + lg) ^ (krow & 7)) * 8)]);
        s0[n] = __builtin_amdgcn_mfma_f32_16x16x32_bf16(kf0, qf[0][0], s0[n], 0, 0, 0);
        s0[n] = __builtin_amdgcn_mfma_f32_16x16x32_bf16(kf1, qf[0][1], s0[n], 0, 0, 0);
        s1[n] = __builtin_amdgcn_mfma_f32_16x16x32_bf16(kf0, qf[1][0], s1[n], 0, 0, 0);
        s1[n] = __builtin_amdgcn_mfma_f32_16x16x32_bf16(kf1, qf[1][1], s1[n], 0, 0, 0);
      }
      __builtin_amdgcn_s_setprio(0);

      // softcap (scale pre-folded into Q): p = xs*(1 - c3*xs^2) - 16
      const int k0 = kt * 64;
      #pragma unroll
      for (int n = 0; n < 4; ++n) {
        #pragma unroll
        for (int r = 0; r < 4; ++r) {
          float xs = s0[n][r];
          s0[n][r] = fmaf(xs, fmaf(xs * xs, -6.40607e-5f, 1.0f), -16.0f);
          xs = s1[n][r];
          s1[n][r] = fmaf(xs, fmaf(xs * xs, -6.40607e-5f, 1.0f), -16.0f);
        }
      }
      // causal mask: key = k0+16n+4lg+r (row of sT), qrow = wrow+s*16+lr (col)
      if (causal && (k0 + 63 > wrow)) {
        #pragma unroll
        for (int n = 0; n < 4; ++n) {
          const int keyb = k0 + n * 16 + lg * 4;
          #pragma unroll
          for (int r = 0; r < 4; ++r)
            if (keyb + r > wrow + lr) s0[n][r] = -1e30f;
        }
      }
      if (causal && (k0 + 63 > wrow + 16)) {
        #pragma unroll
        for (int n = 0; n < 4; ++n) {
          const int keyb = k0 + n * 16 + lg * 4;
          #pragma unroll
          for (int r = 0; r < 4; ++r)
            if (keyb + r > wrow + 16 + lr) s1[n][r] = -1e30f;
        }
      }

      // exp2 + in-register bf16 pack: w[2n+rh] = pk(p[n][2rh], p[n][2rh+1])
      unsigned int w0[8], w1[8];
      #pragma unroll
      for (int n = 0; n < 4; ++n) {
        const float a0 = EXP2(s0[n][0]);
        const float a1 = EXP2(s0[n][1]);
        const float a2 = EXP2(s0[n][2]);
        const float a3 = EXP2(s0[n][3]);
        plt0 += (a0 + a1) + (a2 + a3);
        w0[2 * n] = cvt_pk_bf16(a0, a1);
        w0[2 * n + 1] = cvt_pk_bf16(a2, a3);
        const float c0 = EXP2(s1[n][0]);
        const float c1 = EXP2(s1[n][1]);
        const float c2 = EXP2(s1[n][2]);
        const float c3 = EXP2(s1[n][3]);
        plt1 += (c0 + c1) + (c2 + c3);
        w1[2 * n] = cvt_pk_bf16(c0, c1);
        w1[2 * n + 1] = cvt_pk_bf16(c2, c3);
      }
      short8 pf0[2], pf1[2];
      #pragma unroll
      for (int ks = 0; ks < 2; ++ks) {
        u32x4 a = {w0[4 * ks], w0[4 * ks + 1], w0[4 * ks + 2], w0[4 * ks + 3]};
        u32x4 c = {w1[4 * ks], w1[4 * ks + 1], w1[4 * ks + 2], w1[4 * ks + 3]};
        pf0[ks] = __builtin_bit_cast(short8, a);
        pf1[ks] = __builtin_bit_cast(short8, c);
      }

      // PV both sets; V fragment = 2x b64 at pi-permuted cols (shared)
      const int voff = 4 * (lg & 1);
      __builtin_amdgcn_s_setprio(1);
      #pragma unroll
      for (int ks = 0; ks < 2; ++ks) {
        const int gA = 4 * ks + (lg >> 1);
        #pragma unroll
        for (int n = 0; n < 4; ++n) {
          const int vd = n * 16 + lr;
          const int vb_ = vd * 64;
          const int sw = vd & 7;
          const uint2 vlo = *reinterpret_cast<const uint2*>(
              &Vs[v2][vb_ + ((gA ^ sw) * 8 + voff)]);
          const uint2 vhi = *reinterpret_cast<const uint2*>(
              &Vs[v2][vb_ + (((gA + 2) ^ sw) * 8 + voff)]);
          u32x4 vv = {vlo.x, vlo.y, vhi.x, vhi.y};
          short8 vfr = __builtin_bit_cast(short8, vv);
          o0[n] = __builtin_amdgcn_mfma_f32_16x16x32_bf16(pf0[ks], vfr, o0[n], 0, 0, 0);
          o1[n] = __builtin_amdgcn_mfma_f32_16x16x32_bf16(pf1[ks], vfr, o1[n], 0, 0, 0);
        }
      }
      __builtin_amdgcn_s_setprio(0);
      k3 = (k3 == 2) ? 0 : (k3 + 1);
      v2 ^= 1;
    }

    // epilogue per set
    const bool full = (lo == 0) && (hi == ts);
    #pragma unroll
    for (int s = 0; s < 2; ++s) {
      float ls = s ? plt1 : plt0;
      ls += __shfl_xor(ls, 16, 64);
      ls += __shfl_xor(ls, 32, 64);
      // every lane now holds denom for qrow = wrow + s*16 + lr
      const f32x4* oa = s ? o1 : o0;
      if (full) {
        #pragma unroll
        for (int r = 0; r < 4; ++r) {
          const float den = __shfl(ls, lg * 4 + r, 64);  // denom of row lg*4+r
          const float invl = __builtin_amdgcn_rcpf(den);
          const int qg_ = wrow + s * 16 + lg * 4 + r;
          #pragma unroll
          for (int n = 0; n < 4; ++n)
            y[((size_t)b * L_SEQ + qg_) * DM + h * HDIM + n * 16 + lr] =
                __float2bfloat16(oa[n][r] * invl);
        }
      } else {
        if (lane < 16)
          pd[((size_t)half * NB * NH + bh) * L_SEQ + wrow + s * 16 + lane] = ls;
        #pragma unroll
        for (int r = 0; r < 4; ++r) {
          const int qg_ = wrow + s * 16 + lg * 4 + r;
          #pragma unroll
          for (int n = 0; n < 4; ++n)
            pO[(((size_t)half * NB + b) * L_SEQ + qg_) * DM + h * HDIM + n * 16 + lr] =
                __float2bfloat16(oa[n][r]);
        }
      }
    }
  }
}

extern "C" void kernel_launch(void* const* d_in, const int* in_sizes, int n_in,
                              void* d_out, int out_size, void* d_ws, size_t ws_size,
                              hipStream_t stream) {
  (void)in_sizes; (void)n_in; (void)out_size; (void)ws_size;
  const float* x  = (const float*)d_in[0];
  const float* Wq = (const float*)d_in[1];
  const float* bq = (const float*)d_in[2];
  const float* Wk = (const float*)d_in[3];
  const float* bk = (const float*)d_in[4];
  const float* Wv = (const float*)d_in[5];
  const float* bv = (const float*)d_in[6];
  const float* Wo = (const float*)d_in[7];
  const float* bo = (const float*)d_in[8];
  const float* qg = (const float*)d_in[9];
  const float* kg = (const float*)d_in[10];
  const float* rc = (const float*)d_in[11];
  const float* rs = (const float*)d_in[12];
  const int* causal = (const int*)d_in[13];
  float* out = (float*)d_out;

  char* ws = (char*)d_ws;
  size_t off = 0;
  auto alloc = [&](size_t bytes) -> char* {
    char* p = ws + off;
    off += (bytes + 255) & ~(size_t)255;
    return p;
  };
  bf16* xb    = (bf16*)alloc((size_t)4096 * 1024 * 2);
  bf16* wqkvt = (bf16*)alloc((size_t)1536 * 1024 * 2);
  bf16* wot   = (bf16*)alloc((size_t)1024 * 1024 * 2);
  bf16* vt    = (bf16*)alloc((size_t)NB * NKV * HDIM * L_SEQ * 2);
  bf16* qb    = (bf16*)alloc((size_t)NB * NH * L_SEQ * HDIM * 2);
  bf16* kb    = (bf16*)alloc((size_t)NB * NKV * L_SEQ * HDIM * 2);
  bf16* y     = (bf16*)alloc((size_t)4096 * 1024 * 2);
  bf16* pO    = (bf16*)alloc((size_t)2 * NB * L_SEQ * DM * 2);
  float* pd   = (float*)alloc((size_t)2 * NB * NH * L_SEQ * 4);
  bf16* wqt   = wqkvt;
  bf16* wkt   = wqkvt + (size_t)1024 * 1024;
  bf16* wvt   = wqkvt + (size_t)1280 * 1024;

  // prep: 4 weight transposes + x->bf16 conversion in one launch
  k_prep<<<dim3(32, 32, 5), dim3(32, 8), 0, stream>>>(Wq, Wk, Wv, Wo, x,
                                                      wqt, wkt, wvt, wot, (ushort*)xb);

  // merged QKV projection: Q fused rms+rope (gamma pre-scaled) -> qb,
  // K fused -> kb, V -> Vt
  k_gemm<6><<<dim3(12, 64), 256, 0, stream>>>(xb, wqkvt, bq, bk, bv, qg, kg, rc, rs,
                                              qb, kb, vt, causal, 4096, 1536, 1024);

  k_attn<<<dim3(8, NB * NH, 2), 256, 0, stream>>>(qb, kb, vt, y, pO, pd, causal);

  // Wo projection with fused split-K combine on heavy causal rows
  k_gemm<1><<<dim3(8, 64), 256, 0, stream>>>(y, wot, bo, nullptr, nullptr, nullptr, nullptr,
                                             nullptr, nullptr, out, pO, pd, causal,
                                             4096, 1024, 1024);
}